// Round 1
// baseline (327.260 us; speedup 1.0000x reference)
//
#include <hip/hip_runtime.h>

// Problem: B=128, T=512, C=128, H=64 gated causal attention head, fp32.
// Round 0: correctness-first fp32 baseline.
//   Kernel 1 (gate_qkv): fused  xg = x*sigmoid(x@Wg+bg);  q/k/v = xg@W{q,k,v}
//     64 rows/block, x tile in LDS (stride 132 -> 2-way max conflicts),
//     W staged in 64-row halves (stride 68). Register tiles 4x8 (gate), 4x4 (qkv).
//   Kernel 2 (attn): flash-style online softmax. 64-row Q-tile per block,
//     32-row K/V tiles. LDS strides 68/36 audited for <=2-way conflicts.
// Scratch: q,k,v in d_ws -> needs 3*128*512*64*4 = 50.3 MB of ws_size.

#define BB 128
#define TB 512
#define CC 128
#define HH 64

static constexpr float SCALE = 0.088388347648318447f; // C^-0.5 (NOT H^-0.5)

__global__ __launch_bounds__(256, 3) void gate_qkv_kernel(
    const float* __restrict__ x, const float* __restrict__ Wg,
    const float* __restrict__ bg, const float* __restrict__ Wk,
    const float* __restrict__ Wq, const float* __restrict__ Wv,
    float* __restrict__ qo, float* __restrict__ ko, float* __restrict__ vo)
{
    __shared__ float xs[64 * 132];   // x tile, later overwritten in-place with xg
    __shared__ float wsh[64 * 68];   // half of one projection weight

    const int tid = threadIdx.x;
    const int R0 = blockIdx.x * 64;  // global row base (BT rows total)

    // ---- load x tile 64x128 (coalesced: addr = 4*fid) ----
#pragma unroll
    for (int kk = 0; kk < 8; ++kk) {
        int fid = tid + 256 * kk;        // 0..2047 float4s
        int r = fid >> 5, c4 = fid & 31;
        *(float4*)(xs + r * 132 + c4 * 4) =
            *(const float4*)(x + (R0 + r) * CC + c4 * 4);
    }
    __syncthreads();

    // ---- gate: acc[4 rows][8 cols], rows rg+16a (stride-16 => 2-way banks) ----
    {
        const int cg = tid & 15, rg = tid >> 4;
        const int c0 = cg * 8;
        float acc[4][8];
#pragma unroll
        for (int a = 0; a < 4; ++a)
#pragma unroll
            for (int j = 0; j < 8; ++j) acc[a][j] = 0.f;

        for (int cp = 0; cp < CC; cp += 4) {
            float xq[4][4];
#pragma unroll
            for (int a = 0; a < 4; ++a)
                *(float4*)xq[a] = *(const float4*)(xs + (rg + 16 * a) * 132 + cp);
#pragma unroll
            for (int dd = 0; dd < 4; ++dd) {
                float w[8];
                *(float4*)(w)     = *(const float4*)(Wg + (cp + dd) * CC + c0);
                *(float4*)(w + 4) = *(const float4*)(Wg + (cp + dd) * CC + c0 + 4);
#pragma unroll
                for (int a = 0; a < 4; ++a)
#pragma unroll
                    for (int j = 0; j < 8; ++j)
                        acc[a][j] = fmaf(xq[a][dd], w[j], acc[a][j]);
            }
        }

        float bgv[8];
        *(float4*)bgv       = *(const float4*)(bg + c0);
        *(float4*)(bgv + 4) = *(const float4*)(bg + c0 + 4);

        float xgv[4][8];
#pragma unroll
        for (int a = 0; a < 4; ++a) {
            float xr[8];
            *(float4*)xr       = *(const float4*)(xs + (rg + 16 * a) * 132 + c0);
            *(float4*)(xr + 4) = *(const float4*)(xs + (rg + 16 * a) * 132 + c0 + 4);
#pragma unroll
            for (int j = 0; j < 8; ++j) {
                float s = acc[a][j] + bgv[j];
                float g = 1.f / (1.f + __expf(-s));
                xgv[a][j] = xr[j] * g;
            }
        }
        __syncthreads();   // all gate reads of xs done before in-place overwrite
#pragma unroll
        for (int a = 0; a < 4; ++a) {
            *(float4*)(xs + (rg + 16 * a) * 132 + c0)     = *(const float4*)xgv[a];
            *(float4*)(xs + (rg + 16 * a) * 132 + c0 + 4) = *(const float4*)(xgv[a] + 4);
        }
        // next barrier (top of W staging) makes xg visible to all
    }

    // ---- q/k/v projections: acc[4 rows][4 cols], W staged in halves ----
    const float* Ws[3] = {Wk, Wq, Wv};
    float* Os[3] = {ko, qo, vo};
    const int cg = tid & 15, rg = tid >> 4;
    const int c0 = cg * 4;

    for (int wi = 0; wi < 3; ++wi) {
        const float* W = Ws[wi];
        float acc[4][4];
#pragma unroll
        for (int a = 0; a < 4; ++a)
#pragma unroll
            for (int j = 0; j < 4; ++j) acc[a][j] = 0.f;

        for (int half = 0; half < 2; ++half) {
            __syncthreads();  // previous wsh users done / xg writes visible
#pragma unroll
            for (int kk = 0; kk < 4; ++kk) {
                int fid = tid + 256 * kk;     // 64x64 floats = 1024 f4
                int r = fid >> 4, c4 = fid & 15;
                *(float4*)(wsh + r * 68 + c4 * 4) =
                    *(const float4*)(W + (half * 64 + r) * HH + c4 * 4);
            }
            __syncthreads();

            for (int cp = 0; cp < 64; cp += 4) {
                float xq[4][4], wv4[4][4];
#pragma unroll
                for (int a = 0; a < 4; ++a)
                    *(float4*)xq[a] =
                        *(const float4*)(xs + (rg + 16 * a) * 132 + half * 64 + cp);
#pragma unroll
                for (int dd = 0; dd < 4; ++dd)
                    *(float4*)wv4[dd] = *(const float4*)(wsh + (cp + dd) * 68 + c0);
#pragma unroll
                for (int a = 0; a < 4; ++a)
#pragma unroll
                    for (int dd = 0; dd < 4; ++dd)
#pragma unroll
                        for (int j = 0; j < 4; ++j)
                            acc[a][j] = fmaf(xq[a][dd], wv4[dd][j], acc[a][j]);
            }
        }
        float* O = Os[wi];
#pragma unroll
        for (int a = 0; a < 4; ++a)   // store addr = 4*tid within row-group: coalesced
            *(float4*)(O + (R0 + rg + 16 * a) * HH + c0) = *(const float4*)acc[a];
    }
}

__global__ __launch_bounds__(256, 3) void attn_kernel(
    const float* __restrict__ q, const float* __restrict__ k,
    const float* __restrict__ v, float* __restrict__ out)
{
    __shared__ float qs[64 * 68];
    __shared__ float ks[32 * 68];
    __shared__ float vs[32 * 68];
    __shared__ float ss[64 * 36];

    const int tid = threadIdx.x;
    const int qt = blockIdx.x;       // 0..7 -> 64-row q tile
    const int b  = blockIdx.y;       // 0..127
    const int q0 = qt * 64;
    const int base = b * TB * HH;

#pragma unroll
    for (int kk = 0; kk < 4; ++kk) {
        int fid = tid + 256 * kk;
        int r = fid >> 4, c4 = fid & 15;
        *(float4*)(qs + r * 68 + c4 * 4) =
            *(const float4*)(q + base + (q0 + r) * HH + c4 * 4);
    }

    const int rr = tid >> 2, part = tid & 3;   // O-owner mapping: row rr, cols part*16..+15
    const int cop = part * 16;
    const int jg = tid & 7, ig = tid >> 3;     // S mapping: i = ig+32a, j = jg+8j

    float O[16];
#pragma unroll
    for (int i = 0; i < 16; ++i) O[i] = 0.f;
    float mrow = -1e30f, lrow = 0.f;

    const int nkt = 2 * qt + 2;      // 32-row k tiles covering 0..q0+63
    for (int kt = 0; kt < nkt; ++kt) {
        __syncthreads();             // prev-iter PV readers done; qs store visible (iter 0)
        const int k0 = kt * 32;
#pragma unroll
        for (int kk = 0; kk < 2; ++kk) {
            int fid = tid + 256 * kk;
            int r = fid >> 4, c4 = fid & 15;
            *(float4*)(ks + r * 68 + c4 * 4) =
                *(const float4*)(k + base + (k0 + r) * HH + c4 * 4);
            *(float4*)(vs + r * 68 + c4 * 4) =
                *(const float4*)(v + base + (k0 + r) * HH + c4 * 4);
        }
        __syncthreads();

        // ---- S = q k^T  (2x4 register tile per thread) ----
        float sacc[2][4];
#pragma unroll
        for (int a = 0; a < 2; ++a)
#pragma unroll
            for (int j = 0; j < 4; ++j) sacc[a][j] = 0.f;

        for (int d = 0; d < HH; d += 4) {
            float qv[2][4], kv[4][4];
#pragma unroll
            for (int a = 0; a < 2; ++a)
                *(float4*)qv[a] = *(const float4*)(qs + (ig + 32 * a) * 68 + d);
#pragma unroll
            for (int j = 0; j < 4; ++j)
                *(float4*)kv[j] = *(const float4*)(ks + (jg + 8 * j) * 68 + d);
#pragma unroll
            for (int a = 0; a < 2; ++a)
#pragma unroll
                for (int j = 0; j < 4; ++j)
#pragma unroll
                    for (int dd = 0; dd < 4; ++dd)
                        sacc[a][j] = fmaf(qv[a][dd], kv[j][dd], sacc[a][j]);
        }

        const bool diag = (kt >= 2 * qt);   // only last two tiles cross the diagonal
#pragma unroll
        for (int a = 0; a < 2; ++a)
#pragma unroll
            for (int j = 0; j < 4; ++j) {
                int gi = ig + 32 * a, gj = jg + 8 * j;
                float s = sacc[a][j] * SCALE;
                if (diag && (k0 + gj) > (q0 + gi)) s = -1e30f;
                ss[gi * 36 + gj] = s;
            }
        __syncthreads();

        // ---- online softmax row stats (4 threads per row, shfl-combined) ----
        float pv[8];
        float mloc = -1e30f;
#pragma unroll
        for (int jj = 0; jj < 8; ++jj) {
            pv[jj] = ss[rr * 36 + part * 8 + jj];
            mloc = fmaxf(mloc, pv[jj]);
        }
        mloc = fmaxf(mloc, __shfl_xor(mloc, 1));
        mloc = fmaxf(mloc, __shfl_xor(mloc, 2));
        float m_new = fmaxf(mrow, mloc);
        float alpha = __expf(mrow - m_new);
        float ssum = 0.f;
#pragma unroll
        for (int jj = 0; jj < 8; ++jj) {
            float e = __expf(pv[jj] - m_new);
            ss[rr * 36 + part * 8 + jj] = e;
            ssum += e;
        }
        ssum += __shfl_xor(ssum, 1);
        ssum += __shfl_xor(ssum, 2);
        lrow = lrow * alpha + ssum;
        mrow = m_new;
        __syncthreads();

        // ---- O = O*alpha + P @ V ----
#pragma unroll
        for (int i = 0; i < 16; ++i) O[i] *= alpha;
        for (int j4 = 0; j4 < 32; j4 += 4) {
            float pq[4];
            *(float4*)pq = *(const float4*)(ss + rr * 36 + j4);
#pragma unroll
            for (int jj = 0; jj < 4; ++jj) {
                float p = pq[jj];
#pragma unroll
                for (int qq = 0; qq < 4; ++qq) {
                    float4 vv = *(const float4*)(vs + (j4 + jj) * 68 + cop + qq * 4);
                    O[qq * 4 + 0] = fmaf(p, vv.x, O[qq * 4 + 0]);
                    O[qq * 4 + 1] = fmaf(p, vv.y, O[qq * 4 + 1]);
                    O[qq * 4 + 2] = fmaf(p, vv.z, O[qq * 4 + 2]);
                    O[qq * 4 + 3] = fmaf(p, vv.w, O[qq * 4 + 3]);
                }
            }
        }
    }

    const float inv = 1.f / lrow;
#pragma unroll
    for (int qq = 0; qq < 4; ++qq) {
        float4 o4 = make_float4(O[qq * 4 + 0] * inv, O[qq * 4 + 1] * inv,
                                O[qq * 4 + 2] * inv, O[qq * 4 + 3] * inv);
        *(float4*)(out + base + (q0 + rr) * HH + cop + qq * 4) = o4;
    }
}

extern "C" void kernel_launch(void* const* d_in, const int* in_sizes, int n_in,
                              void* d_out, int out_size, void* d_ws, size_t ws_size,
                              hipStream_t stream) {
    const float* x  = (const float*)d_in[0];
    const float* Wg = (const float*)d_in[1];
    const float* bg = (const float*)d_in[2];
    const float* Wk = (const float*)d_in[3];
    const float* Wq = (const float*)d_in[4];
    const float* Wv = (const float*)d_in[5];
    float* out = (float*)d_out;

    float* ws = (float*)d_ws;
    const size_t BTH = (size_t)BB * TB * HH;   // 4,194,304
    float* qo = ws;
    float* ko = ws + BTH;
    float* vo = ws + 2 * BTH;                  // total 50.3 MB of d_ws

    hipLaunchKernelGGL(gate_qkv_kernel, dim3(BB * TB / 64), dim3(256), 0, stream,
                       x, Wg, bg, Wk, Wq, Wv, qo, ko, vo);
    hipLaunchKernelGGL(attn_kernel, dim3(8, BB), dim3(256), 0, stream,
                       qo, ko, vo, out);
}

// Round 2
// 188.013 us; speedup vs baseline: 1.7406x; 1.7406x over previous
//
#include <hip/hip_runtime.h>

// Round 2: bf16-MFMA flash attention + balanced q-tile pairing.
//  Kernel 1 (gate_qkv): fp32 GEMMs as round 1, but outputs bf16:
//    q,k row-major bf16 [B][T][64]; v TRANSPOSED bf16 vT[B][64][T]
//    (LDS transpose reusing x tile) so attn B-frags are ds_read_b128.
//  Kernel 2 (attn): mfma_f32_16x16x32_bf16 for QK^T and PV.
//    Block = 4 waves = 64 q-rows; two q-tiles (qt, 7-qt) per block ->
//    uniform 9 kv-tile iters/block, grid 4x128 = 512 blocks.
//    Softmax stats fully in registers (quad shfl_xor); P via LDS round-trip
//    (C-layout -> A-layout, m120 pattern). LDS strides 72/76 audited <=2-way.
// ws: q,k,vT bf16 = 3 * 4.2M * 2B = 25.2 MB.

#define BB 128
#define TB 512
#define CC 128
#define HH 64

static constexpr float SCALE = 0.088388347648318447f; // C^-0.5 (NOT H^-0.5)

typedef __attribute__((ext_vector_type(8))) short bf16x8;
typedef __attribute__((ext_vector_type(8))) unsigned short u16x8;
typedef __attribute__((ext_vector_type(4))) float f32x4;

__device__ inline unsigned short f2bf(float f) {
    union { float f; unsigned u; } x; x.f = f;
    unsigned r = x.u + 0x7fff + ((x.u >> 16) & 1);   // RNE
    return (unsigned short)(r >> 16);
}

__global__ __launch_bounds__(256, 3) void gate_qkv_kernel(
    const float* __restrict__ x, const float* __restrict__ Wg,
    const float* __restrict__ bg, const float* __restrict__ Wk,
    const float* __restrict__ Wq, const float* __restrict__ Wv,
    unsigned short* __restrict__ qo, unsigned short* __restrict__ ko,
    unsigned short* __restrict__ vto)
{
    __shared__ float xs[64 * 132];   // x tile -> xg in-place -> v-tile (stride 68) for transpose
    __shared__ float wsh[64 * 68];   // half of one projection weight

    const int tid = threadIdx.x;
    const int R0 = blockIdx.x * 64;  // global row base; blocks never straddle a batch (512%64==0)

    // ---- load x tile 64x128 ----
#pragma unroll
    for (int kk = 0; kk < 8; ++kk) {
        int fid = tid + 256 * kk;
        int r = fid >> 5, c4 = fid & 31;
        *(float4*)(xs + r * 132 + c4 * 4) =
            *(const float4*)(x + (R0 + r) * CC + c4 * 4);
    }
    __syncthreads();

    // ---- gate GEMM + sigmoid, xg written back into xs ----
    {
        const int cg = tid & 15, rg = tid >> 4;
        const int c0 = cg * 8;
        float acc[4][8];
#pragma unroll
        for (int a = 0; a < 4; ++a)
#pragma unroll
            for (int j = 0; j < 8; ++j) acc[a][j] = 0.f;

        for (int cp = 0; cp < CC; cp += 4) {
            float xq[4][4];
#pragma unroll
            for (int a = 0; a < 4; ++a)
                *(float4*)xq[a] = *(const float4*)(xs + (rg + 16 * a) * 132 + cp);
#pragma unroll
            for (int dd = 0; dd < 4; ++dd) {
                float w[8];
                *(float4*)(w)     = *(const float4*)(Wg + (cp + dd) * CC + c0);
                *(float4*)(w + 4) = *(const float4*)(Wg + (cp + dd) * CC + c0 + 4);
#pragma unroll
                for (int a = 0; a < 4; ++a)
#pragma unroll
                    for (int j = 0; j < 8; ++j)
                        acc[a][j] = fmaf(xq[a][dd], w[j], acc[a][j]);
            }
        }

        float bgv[8];
        *(float4*)bgv       = *(const float4*)(bg + c0);
        *(float4*)(bgv + 4) = *(const float4*)(bg + c0 + 4);

        float xgv[4][8];
#pragma unroll
        for (int a = 0; a < 4; ++a) {
            float xr[8];
            *(float4*)xr       = *(const float4*)(xs + (rg + 16 * a) * 132 + c0);
            *(float4*)(xr + 4) = *(const float4*)(xs + (rg + 16 * a) * 132 + c0 + 4);
#pragma unroll
            for (int j = 0; j < 8; ++j) {
                float s = acc[a][j] + bgv[j];
                float g = 1.f / (1.f + __expf(-s));
                xgv[a][j] = xr[j] * g;
            }
        }
        __syncthreads();
#pragma unroll
        for (int a = 0; a < 4; ++a) {
            *(float4*)(xs + (rg + 16 * a) * 132 + c0)     = *(const float4*)xgv[a];
            *(float4*)(xs + (rg + 16 * a) * 132 + c0 + 4) = *(const float4*)(xgv[a] + 4);
        }
    }

    // ---- q/k/v projections (fp32), outputs bf16; v transposed via LDS ----
    const float* Ws[3] = {Wk, Wq, Wv};
    const int cg = tid & 15, rg = tid >> 4;
    const int c0 = cg * 4;

    for (int wi = 0; wi < 3; ++wi) {
        const float* W = Ws[wi];
        float acc[4][4];
#pragma unroll
        for (int a = 0; a < 4; ++a)
#pragma unroll
            for (int j = 0; j < 4; ++j) acc[a][j] = 0.f;

        for (int half = 0; half < 2; ++half) {
            __syncthreads();
#pragma unroll
            for (int kk = 0; kk < 4; ++kk) {
                int fid = tid + 256 * kk;
                int r = fid >> 4, c4 = fid & 15;
                *(float4*)(wsh + r * 68 + c4 * 4) =
                    *(const float4*)(W + (half * 64 + r) * HH + c4 * 4);
            }
            __syncthreads();

            for (int cp = 0; cp < 64; cp += 4) {
                float xq[4][4], wv4[4][4];
#pragma unroll
                for (int a = 0; a < 4; ++a)
                    *(float4*)xq[a] =
                        *(const float4*)(xs + (rg + 16 * a) * 132 + half * 64 + cp);
#pragma unroll
                for (int dd = 0; dd < 4; ++dd)
                    *(float4*)wv4[dd] = *(const float4*)(wsh + (cp + dd) * 68 + c0);
#pragma unroll
                for (int a = 0; a < 4; ++a)
#pragma unroll
                    for (int dd = 0; dd < 4; ++dd)
#pragma unroll
                        for (int j = 0; j < 4; ++j)
                            acc[a][j] = fmaf(xq[a][dd], wv4[dd][j], acc[a][j]);
            }
        }

        if (wi < 2) {
            unsigned short* O = (wi == 0) ? ko : qo;
#pragma unroll
            for (int a = 0; a < 4; ++a) {
                ushort4 h4;
                h4.x = f2bf(acc[a][0]); h4.y = f2bf(acc[a][1]);
                h4.z = f2bf(acc[a][2]); h4.w = f2bf(acc[a][3]);
                *(ushort4*)(O + (size_t)(R0 + rg + 16 * a) * HH + c0) = h4;
            }
        } else {
            // v: park fp32 tile in xs (stride 68), transpose, store bf16 vT[b][h][t]
            __syncthreads();   // all xs (xg) readers done
#pragma unroll
            for (int a = 0; a < 4; ++a)
                *(float4*)(xs + (rg + 16 * a) * 68 + c0) = *(const float4*)acc[a];
            __syncthreads();
            const int w = tid >> 6, h = tid & 63;
            u16x8 v0, v1;
#pragma unroll
            for (int j = 0; j < 8; ++j) {
                v0[j] = f2bf(xs[(16 * w + j) * 68 + h]);
                v1[j] = f2bf(xs[(16 * w + 8 + j) * 68 + h]);
            }
            const int b = R0 >> 9, t0 = R0 & 511;
            unsigned short* dst = vto + (size_t)b * (HH * TB) + h * TB + t0 + 16 * w;
            *(u16x8*)(dst)     = v0;
            *(u16x8*)(dst + 8) = v1;
        }
    }
}

__global__ __launch_bounds__(256) void attn_kernel(
    const unsigned short* __restrict__ q, const unsigned short* __restrict__ k,
    const unsigned short* __restrict__ vt, float* __restrict__ out)
{
    __shared__ unsigned short ks[64 * 72];   // K tile, row-major [t][h]
    __shared__ unsigned short vs[64 * 72];   // vT tile, [h][t]
    __shared__ unsigned short ps[64 * 76];   // P round-trip, rows 16*wave..

    const int tid  = threadIdx.x;
    const int wave = tid >> 6;
    const int lane = tid & 63;
    const int l15  = lane & 15;
    const int quad = lane >> 4;
    const int pr   = blockIdx.x;             // 0..3 pair index
    const int b    = blockIdx.y;
    const size_t base = (size_t)b * TB * HH; // q/k/out element base (also vT: 64*512)

    for (int pass = 0; pass < 2; ++pass) {
        const int qt = pass ? (7 - pr) : pr;
        const int q0 = qt * 64;

        // Q A-frags straight from global (per-wave 16 rows)
        const unsigned short* qrow = q + base + (size_t)(q0 + 16 * wave + l15) * HH;
        bf16x8 aq0 = *(const bf16x8*)(qrow + quad * 8);
        bf16x8 aq1 = *(const bf16x8*)(qrow + 32 + quad * 8);

        f32x4 o4[4];
        float mrow[4], lrow[4];
#pragma unroll
        for (int nt = 0; nt < 4; ++nt) o4[nt] = (f32x4){0.f, 0.f, 0.f, 0.f};
#pragma unroll
        for (int r = 0; r < 4; ++r) { mrow[r] = -1e30f; lrow[r] = 0.f; }

        for (int kt = 0; kt <= qt; ++kt) {
            const int k0 = kt * 64;
            __syncthreads();   // previous tile's frag reads done
#pragma unroll
            for (int i = 0; i < 2; ++i) {
                int cid = tid + 256 * i;
                int r = cid >> 3, c8 = cid & 7;
                *(bf16x8*)(ks + r * 72 + c8 * 8) =
                    *(const bf16x8*)(k + base + (size_t)(k0 + r) * HH + c8 * 8);
                *(bf16x8*)(vs + r * 72 + c8 * 8) =
                    *(const bf16x8*)(vt + base + (size_t)r * TB + k0 + c8 * 8);
            }
            __syncthreads();

            // ---- S = Q K^T : 4 n-tiles x 2 k-chunks ----
            f32x4 s[4];
#pragma unroll
            for (int nt = 0; nt < 4; ++nt) {
                bf16x8 bk0 = *(const bf16x8*)(ks + (16 * nt + l15) * 72 + quad * 8);
                bf16x8 bk1 = *(const bf16x8*)(ks + (16 * nt + l15) * 72 + 32 + quad * 8);
                f32x4 z = (f32x4){0.f, 0.f, 0.f, 0.f};
                z = __builtin_amdgcn_mfma_f32_16x16x32_bf16(aq0, bk0, z, 0, 0, 0);
                z = __builtin_amdgcn_mfma_f32_16x16x32_bf16(aq1, bk1, z, 0, 0, 0);
                s[nt] = z;
            }

            // ---- scale + causal mask (only diagonal tile) ----
            const bool diag = (kt == qt);
            float mx[4];
#pragma unroll
            for (int r = 0; r < 4; ++r) mx[r] = -1e30f;
#pragma unroll
            for (int nt = 0; nt < 4; ++nt)
#pragma unroll
                for (int r = 0; r < 4; ++r) {
                    float sv = s[nt][r] * SCALE;
                    if (diag && (16 * nt + l15) > (16 * wave + quad * 4 + r)) sv = -1e30f;
                    s[nt][r] = sv;
                    mx[r] = fmaxf(mx[r], sv);
                }

            // ---- online softmax, stats in registers (row = quad*4+r) ----
#pragma unroll
            for (int r = 0; r < 4; ++r) {
                mx[r] = fmaxf(mx[r], __shfl_xor(mx[r], 1));
                mx[r] = fmaxf(mx[r], __shfl_xor(mx[r], 2));
                mx[r] = fmaxf(mx[r], __shfl_xor(mx[r], 4));
                mx[r] = fmaxf(mx[r], __shfl_xor(mx[r], 8));
            }
            float alpha[4], psum[4];
#pragma unroll
            for (int r = 0; r < 4; ++r) {
                float mn = fmaxf(mrow[r], mx[r]);
                alpha[r] = __expf(mrow[r] - mn);
                mrow[r] = mn;
                psum[r] = 0.f;
            }
#pragma unroll
            for (int nt = 0; nt < 4; ++nt)
#pragma unroll
                for (int r = 0; r < 4; ++r) {
                    float e = __expf(s[nt][r] - mrow[r]);
                    psum[r] += e;
                    ps[(16 * wave + quad * 4 + r) * 76 + 16 * nt + l15] = f2bf(e);
                }
#pragma unroll
            for (int r = 0; r < 4; ++r) {
                psum[r] += __shfl_xor(psum[r], 1);
                psum[r] += __shfl_xor(psum[r], 2);
                psum[r] += __shfl_xor(psum[r], 4);
                psum[r] += __shfl_xor(psum[r], 8);
                lrow[r] = lrow[r] * alpha[r] + psum[r];
            }
#pragma unroll
            for (int nt = 0; nt < 4; ++nt)
#pragma unroll
                for (int r = 0; r < 4; ++r) o4[nt][r] *= alpha[r];

            // ---- O += P V  (P via LDS round-trip, wave-private rows) ----
            bf16x8 ap0 = *(const bf16x8*)(ps + (16 * wave + l15) * 76 + quad * 8);
            bf16x8 ap1 = *(const bf16x8*)(ps + (16 * wave + l15) * 76 + 32 + quad * 8);
#pragma unroll
            for (int nt = 0; nt < 4; ++nt) {
                bf16x8 bv0 = *(const bf16x8*)(vs + (16 * nt + l15) * 72 + quad * 8);
                bf16x8 bv1 = *(const bf16x8*)(vs + (16 * nt + l15) * 72 + 32 + quad * 8);
                o4[nt] = __builtin_amdgcn_mfma_f32_16x16x32_bf16(ap0, bv0, o4[nt], 0, 0, 0);
                o4[nt] = __builtin_amdgcn_mfma_f32_16x16x32_bf16(ap1, bv1, o4[nt], 0, 0, 0);
            }
        }

        // ---- epilogue ----
        float inv[4];
#pragma unroll
        for (int r = 0; r < 4; ++r) inv[r] = 1.f / lrow[r];
#pragma unroll
        for (int nt = 0; nt < 4; ++nt)
#pragma unroll
            for (int r = 0; r < 4; ++r)
                out[base + (size_t)(q0 + 16 * wave + quad * 4 + r) * HH + 16 * nt + l15] =
                    o4[nt][r] * inv[r];
    }
}

extern "C" void kernel_launch(void* const* d_in, const int* in_sizes, int n_in,
                              void* d_out, int out_size, void* d_ws, size_t ws_size,
                              hipStream_t stream) {
    const float* x  = (const float*)d_in[0];
    const float* Wg = (const float*)d_in[1];
    const float* bg = (const float*)d_in[2];
    const float* Wk = (const float*)d_in[3];
    const float* Wq = (const float*)d_in[4];
    const float* Wv = (const float*)d_in[5];
    float* out = (float*)d_out;

    unsigned short* ws = (unsigned short*)d_ws;
    const size_t BTH = (size_t)BB * TB * HH;   // 4,194,304
    unsigned short* qo  = ws;
    unsigned short* ko  = ws + BTH;
    unsigned short* vto = ws + 2 * BTH;        // 25.2 MB total

    hipLaunchKernelGGL(gate_qkv_kernel, dim3(BB * TB / 64), dim3(256), 0, stream,
                       x, Wg, bg, Wk, Wq, Wv, qo, ko, vto);
    hipLaunchKernelGGL(attn_kernel, dim3(4, BB), dim3(256), 0, stream,
                       qo, ko, vto, out);
}

// Round 3
// 137.483 us; speedup vs baseline: 2.3804x; 1.3675x over previous
//
#include <hip/hip_runtime.h>

// Round 3: MFMA-ized gate_qkv (attn unchanged from round 2).
//  prep_weights: Wg/Wk/Wq/Wv -> bf16 TRANSPOSED (WT[n][k]) in d_ws.
//  gate_qkv: 128 rows/block, 4 waves x 32 rows (2 m-tiles). All GEMMs via
//    mfma_f32_16x16x32_bf16 with operand swap (a=WT rows, b=x rows) so the
//    C-layout holds 4 contiguous OUTPUT columns per lane:
//      - gate epilogue: ds_read_b64/ds_write_b64 in-place xg update
//      - V projection: C' layout IS vT -> direct global stores, no park
//    Waves own disjoint row-sets -> only 2 __syncthreads total.
//  attn: round-2 bf16 MFMA flash kernel, untouched.
// ws: q,k,vT bf16 (25.2 MB) + bf16 weights (80 KB).

#define BB 128
#define TB 512
#define CC 128
#define HH 64

static constexpr float SCALE = 0.088388347648318447f; // C^-0.5 (NOT H^-0.5)

typedef __attribute__((ext_vector_type(8))) short bf16x8;
typedef __attribute__((ext_vector_type(8))) unsigned short u16x8;
typedef __attribute__((ext_vector_type(4))) float f32x4;

__device__ inline unsigned short f2bf(float f) {
    union { float f; unsigned u; } x; x.f = f;
    unsigned r = x.u + 0x7fff + ((x.u >> 16) & 1);   // RNE
    return (unsigned short)(r >> 16);
}
__device__ inline float bf2f(unsigned short h) {
    union { unsigned u; float f; } x; x.u = ((unsigned)h) << 16;
    return x.f;
}

// ---- weight transpose+convert: WT[n][k] = bf16(W[k][n]) ----
__global__ void prep_weights(const float* __restrict__ Wg, const float* __restrict__ Wk,
                             const float* __restrict__ Wq, const float* __restrict__ Wv,
                             unsigned short* __restrict__ WgT, unsigned short* __restrict__ WkT,
                             unsigned short* __restrict__ WqT, unsigned short* __restrict__ WvT)
{
    int idx = blockIdx.x * 256 + threadIdx.x;        // 0..40959
    if (idx < 16384) {                               // Wg 128x128
        int n = idx >> 7, k = idx & 127;
        WgT[idx] = f2bf(Wg[k * CC + n]);
    } else {
        int j = idx - 16384;                         // 3 x (64x128)
        int mtx = j >> 13;                           // 0..2
        int r = j & 8191;
        int n = r >> 7, k = r & 127;
        const float* W = (mtx == 0) ? Wk : (mtx == 1) ? Wq : Wv;
        unsigned short* WT = (mtx == 0) ? WkT : (mtx == 1) ? WqT : WvT;
        WT[r] = f2bf(W[k * HH + n]);
    }
}

__global__ __launch_bounds__(256, 3) void gate_qkv_kernel(
    const float* __restrict__ x, const float* __restrict__ bg,
    const unsigned short* __restrict__ WgT, const unsigned short* __restrict__ WkT,
    const unsigned short* __restrict__ WqT, const unsigned short* __restrict__ WvT,
    unsigned short* __restrict__ qo, unsigned short* __restrict__ ko,
    unsigned short* __restrict__ vto)
{
    __shared__ unsigned short xsb[128 * 136];   // x tile -> xg in-place (bf16)

    const int tid  = threadIdx.x;
    const int wv   = tid >> 6;
    const int lane = tid & 63;
    const int l15  = lane & 15;
    const int quad = lane >> 4;
    const int R0   = blockIdx.x * 128;          // 512 % 128 == 0: one batch per block

    // ---- stage x -> bf16 LDS ----
#pragma unroll
    for (int it = 0; it < 16; ++it) {
        int fid = tid + 256 * it;               // 4096 float4s
        int r = fid >> 5, c4 = fid & 31;
        float4 xv = *(const float4*)(x + (size_t)(R0 + r) * CC + c4 * 4);
        ushort4 h;
        h.x = f2bf(xv.x); h.y = f2bf(xv.y); h.z = f2bf(xv.z); h.w = f2bf(xv.w);
        *(ushort4*)(xsb + r * 136 + c4 * 4) = h;
    }
    __syncthreads();

    // ---- B-frags: this wave's 32 x-rows (2 m-tiles x 4 k-chunks) ----
    bf16x8 bx[2][4];
#pragma unroll
    for (int mt = 0; mt < 2; ++mt)
#pragma unroll
        for (int kc = 0; kc < 4; ++kc)
            bx[mt][kc] = *(const bf16x8*)(xsb + (32 * wv + 16 * mt + l15) * 136 +
                                          kc * 32 + quad * 8);

    // ---- gate GEMM: D'[n][m] = sum_k WgT[n][k] xg... (x) ----
    f32x4 acc[8][2];
#pragma unroll
    for (int nt = 0; nt < 8; ++nt)
#pragma unroll
        for (int mt = 0; mt < 2; ++mt) acc[nt][mt] = (f32x4){0.f, 0.f, 0.f, 0.f};

#pragma unroll
    for (int nt = 0; nt < 8; ++nt) {
        bf16x8 aw[4];
#pragma unroll
        for (int kc = 0; kc < 4; ++kc)
            aw[kc] = *(const bf16x8*)(WgT + (16 * nt + l15) * CC + kc * 32 + quad * 8);
#pragma unroll
        for (int mt = 0; mt < 2; ++mt)
#pragma unroll
            for (int kc = 0; kc < 4; ++kc)
                acc[nt][mt] = __builtin_amdgcn_mfma_f32_16x16x32_bf16(
                    aw[kc], bx[mt][kc], acc[nt][mt], 0, 0, 0);
    }

    // ---- gate epilogue: sigmoid, xg = x*g, in-place (wave-private rows) ----
#pragma unroll
    for (int nt = 0; nt < 8; ++nt) {
        float4 bgv = *(const float4*)(bg + 16 * nt + quad * 4);
#pragma unroll
        for (int mt = 0; mt < 2; ++mt) {
            int m = 32 * wv + 16 * mt + l15;
            unsigned short* p = xsb + m * 136 + 16 * nt + quad * 4;
            ushort4 xb = *(const ushort4*)p;
            float s0 = acc[nt][mt][0] + bgv.x;
            float s1 = acc[nt][mt][1] + bgv.y;
            float s2 = acc[nt][mt][2] + bgv.z;
            float s3 = acc[nt][mt][3] + bgv.w;
            ushort4 o;
            o.x = f2bf(bf2f(xb.x) / (1.f + __expf(-s0)));
            o.y = f2bf(bf2f(xb.y) / (1.f + __expf(-s1)));
            o.z = f2bf(bf2f(xb.z) / (1.f + __expf(-s2)));
            o.w = f2bf(bf2f(xb.w) / (1.f + __expf(-s3)));
            *(ushort4*)p = o;
        }
    }
    __syncthreads();   // xg writes visible (cross-lane frag reads next)

    // ---- reload B-frags (now xg) ----
#pragma unroll
    for (int mt = 0; mt < 2; ++mt)
#pragma unroll
        for (int kc = 0; kc < 4; ++kc)
            bx[mt][kc] = *(const bf16x8*)(xsb + (32 * wv + 16 * mt + l15) * 136 +
                                          kc * 32 + quad * 8);

    // ---- q/k/v projections ----
    const int b = R0 >> 9, t0 = R0 & 511;
    for (int pj = 0; pj < 3; ++pj) {
        const unsigned short* WT = (pj == 0) ? WkT : (pj == 1) ? WqT : WvT;
        f32x4 pacc[4][2];
#pragma unroll
        for (int nt = 0; nt < 4; ++nt)
#pragma unroll
            for (int mt = 0; mt < 2; ++mt) pacc[nt][mt] = (f32x4){0.f, 0.f, 0.f, 0.f};

#pragma unroll
        for (int nt = 0; nt < 4; ++nt) {
            bf16x8 aw[4];
#pragma unroll
            for (int kc = 0; kc < 4; ++kc)
                aw[kc] = *(const bf16x8*)(WT + (16 * nt + l15) * CC + kc * 32 + quad * 8);
#pragma unroll
            for (int mt = 0; mt < 2; ++mt)
#pragma unroll
                for (int kc = 0; kc < 4; ++kc)
                    pacc[nt][mt] = __builtin_amdgcn_mfma_f32_16x16x32_bf16(
                        aw[kc], bx[mt][kc], pacc[nt][mt], 0, 0, 0);
        }

        if (pj < 2) {
            unsigned short* O = (pj == 0) ? ko : qo;
#pragma unroll
            for (int nt = 0; nt < 4; ++nt)
#pragma unroll
                for (int mt = 0; mt < 2; ++mt) {
                    int m = 32 * wv + 16 * mt + l15;
                    ushort4 h;
                    h.x = f2bf(pacc[nt][mt][0]);
                    h.y = f2bf(pacc[nt][mt][1]);
                    h.z = f2bf(pacc[nt][mt][2]);
                    h.w = f2bf(pacc[nt][mt][3]);
                    *(ushort4*)(O + (size_t)(R0 + m) * HH + 16 * nt + quad * 4) = h;
                }
        } else {
            // C' layout IS vT: lane holds h = 16nt+quad*4+r, t = t0 + m
#pragma unroll
            for (int nt = 0; nt < 4; ++nt)
#pragma unroll
                for (int mt = 0; mt < 2; ++mt) {
                    int m = 32 * wv + 16 * mt + l15;
                    unsigned short* dst =
                        vto + (size_t)b * (HH * TB) + (16 * nt + quad * 4) * TB + t0 + m;
#pragma unroll
                    for (int r = 0; r < 4; ++r)
                        dst[r * TB] = f2bf(pacc[nt][mt][r]);
                }
        }
    }
}

__global__ __launch_bounds__(256) void attn_kernel(
    const unsigned short* __restrict__ q, const unsigned short* __restrict__ k,
    const unsigned short* __restrict__ vt, float* __restrict__ out)
{
    __shared__ unsigned short ks[64 * 72];   // K tile, row-major [t][h]
    __shared__ unsigned short vs[64 * 72];   // vT tile, [h][t]
    __shared__ unsigned short ps[64 * 76];   // P round-trip, rows 16*wave..

    const int tid  = threadIdx.x;
    const int wave = tid >> 6;
    const int lane = tid & 63;
    const int l15  = lane & 15;
    const int quad = lane >> 4;
    const int pr   = blockIdx.x;             // 0..3 pair index
    const int b    = blockIdx.y;
    const size_t base = (size_t)b * TB * HH;

    for (int pass = 0; pass < 2; ++pass) {
        const int qt = pass ? (7 - pr) : pr;
        const int q0 = qt * 64;

        const unsigned short* qrow = q + base + (size_t)(q0 + 16 * wave + l15) * HH;
        bf16x8 aq0 = *(const bf16x8*)(qrow + quad * 8);
        bf16x8 aq1 = *(const bf16x8*)(qrow + 32 + quad * 8);

        f32x4 o4[4];
        float mrow[4], lrow[4];
#pragma unroll
        for (int nt = 0; nt < 4; ++nt) o4[nt] = (f32x4){0.f, 0.f, 0.f, 0.f};
#pragma unroll
        for (int r = 0; r < 4; ++r) { mrow[r] = -1e30f; lrow[r] = 0.f; }

        for (int kt = 0; kt <= qt; ++kt) {
            const int k0 = kt * 64;
            __syncthreads();
#pragma unroll
            for (int i = 0; i < 2; ++i) {
                int cid = tid + 256 * i;
                int r = cid >> 3, c8 = cid & 7;
                *(bf16x8*)(ks + r * 72 + c8 * 8) =
                    *(const bf16x8*)(k + base + (size_t)(k0 + r) * HH + c8 * 8);
                *(bf16x8*)(vs + r * 72 + c8 * 8) =
                    *(const bf16x8*)(vt + base + (size_t)r * TB + k0 + c8 * 8);
            }
            __syncthreads();

            f32x4 s[4];
#pragma unroll
            for (int nt = 0; nt < 4; ++nt) {
                bf16x8 bk0 = *(const bf16x8*)(ks + (16 * nt + l15) * 72 + quad * 8);
                bf16x8 bk1 = *(const bf16x8*)(ks + (16 * nt + l15) * 72 + 32 + quad * 8);
                f32x4 z = (f32x4){0.f, 0.f, 0.f, 0.f};
                z = __builtin_amdgcn_mfma_f32_16x16x32_bf16(aq0, bk0, z, 0, 0, 0);
                z = __builtin_amdgcn_mfma_f32_16x16x32_bf16(aq1, bk1, z, 0, 0, 0);
                s[nt] = z;
            }

            const bool diag = (kt == qt);
            float mx[4];
#pragma unroll
            for (int r = 0; r < 4; ++r) mx[r] = -1e30f;
#pragma unroll
            for (int nt = 0; nt < 4; ++nt)
#pragma unroll
                for (int r = 0; r < 4; ++r) {
                    float sv = s[nt][r] * SCALE;
                    if (diag && (16 * nt + l15) > (16 * wave + quad * 4 + r)) sv = -1e30f;
                    s[nt][r] = sv;
                    mx[r] = fmaxf(mx[r], sv);
                }

#pragma unroll
            for (int r = 0; r < 4; ++r) {
                mx[r] = fmaxf(mx[r], __shfl_xor(mx[r], 1));
                mx[r] = fmaxf(mx[r], __shfl_xor(mx[r], 2));
                mx[r] = fmaxf(mx[r], __shfl_xor(mx[r], 4));
                mx[r] = fmaxf(mx[r], __shfl_xor(mx[r], 8));
            }
            float alpha[4], psum[4];
#pragma unroll
            for (int r = 0; r < 4; ++r) {
                float mn = fmaxf(mrow[r], mx[r]);
                alpha[r] = __expf(mrow[r] - mn);
                mrow[r] = mn;
                psum[r] = 0.f;
            }
#pragma unroll
            for (int nt = 0; nt < 4; ++nt)
#pragma unroll
                for (int r = 0; r < 4; ++r) {
                    float e = __expf(s[nt][r] - mrow[r]);
                    psum[r] += e;
                    ps[(16 * wave + quad * 4 + r) * 76 + 16 * nt + l15] = f2bf(e);
                }
#pragma unroll
            for (int r = 0; r < 4; ++r) {
                psum[r] += __shfl_xor(psum[r], 1);
                psum[r] += __shfl_xor(psum[r], 2);
                psum[r] += __shfl_xor(psum[r], 4);
                psum[r] += __shfl_xor(psum[r], 8);
                lrow[r] = lrow[r] * alpha[r] + psum[r];
            }
#pragma unroll
            for (int nt = 0; nt < 4; ++nt)
#pragma unroll
                for (int r = 0; r < 4; ++r) o4[nt][r] *= alpha[r];

            bf16x8 ap0 = *(const bf16x8*)(ps + (16 * wave + l15) * 76 + quad * 8);
            bf16x8 ap1 = *(const bf16x8*)(ps + (16 * wave + l15) * 76 + 32 + quad * 8);
#pragma unroll
            for (int nt = 0; nt < 4; ++nt) {
                bf16x8 bv0 = *(const bf16x8*)(vs + (16 * nt + l15) * 72 + quad * 8);
                bf16x8 bv1 = *(const bf16x8*)(vs + (16 * nt + l15) * 72 + 32 + quad * 8);
                o4[nt] = __builtin_amdgcn_mfma_f32_16x16x32_bf16(ap0, bv0, o4[nt], 0, 0, 0);
                o4[nt] = __builtin_amdgcn_mfma_f32_16x16x32_bf16(ap1, bv1, o4[nt], 0, 0, 0);
            }
        }

        float inv[4];
#pragma unroll
        for (int r = 0; r < 4; ++r) inv[r] = 1.f / lrow[r];
#pragma unroll
        for (int nt = 0; nt < 4; ++nt)
#pragma unroll
            for (int r = 0; r < 4; ++r)
                out[base + (size_t)(q0 + 16 * wave + quad * 4 + r) * HH + 16 * nt + l15] =
                    o4[nt][r] * inv[r];
    }
}

extern "C" void kernel_launch(void* const* d_in, const int* in_sizes, int n_in,
                              void* d_out, int out_size, void* d_ws, size_t ws_size,
                              hipStream_t stream) {
    const float* x  = (const float*)d_in[0];
    const float* Wg = (const float*)d_in[1];
    const float* bg = (const float*)d_in[2];
    const float* Wk = (const float*)d_in[3];
    const float* Wq = (const float*)d_in[4];
    const float* Wv = (const float*)d_in[5];
    float* out = (float*)d_out;

    unsigned short* ws = (unsigned short*)d_ws;
    const size_t BTH = (size_t)BB * TB * HH;   // 4,194,304
    unsigned short* qo  = ws;
    unsigned short* ko  = ws + BTH;
    unsigned short* vto = ws + 2 * BTH;
    unsigned short* WgT = ws + 3 * BTH;        // 128x128
    unsigned short* WkT = WgT + 16384;         // 64x128 each
    unsigned short* WqT = WkT + 8192;
    unsigned short* WvT = WqT + 8192;          // total ws: 25.25 MB

    hipLaunchKernelGGL(prep_weights, dim3(160), dim3(256), 0, stream,
                       Wg, Wk, Wq, Wv, WgT, WkT, WqT, WvT);
    hipLaunchKernelGGL(gate_qkv_kernel, dim3(BB * TB / 128), dim3(256), 0, stream,
                       x, bg, WgT, WkT, WqT, WvT, qo, ko, vto);
    hipLaunchKernelGGL(attn_kernel, dim3(4, BB), dim3(256), 0, stream,
                       qo, ko, vto, out);
}